// Round 5
// baseline (241.285 us; speedup 1.0000x reference)
//
#include <hip/hip_runtime.h>
#include <stdint.h>

#define SEQ   2048
#define DIM   1024
#define BATCH 4

typedef _Float16 f16;
typedef __attribute__((ext_vector_type(8)))  _Float16 f16x8;
typedef __attribute__((ext_vector_type(4)))  _Float16 f16x4;
typedef __attribute__((ext_vector_type(4)))  float    f32x4;
typedef __attribute__((ext_vector_type(16))) float    f32x16;

typedef void __attribute__((address_space(1))) vg_t;
typedef void __attribute__((address_space(3))) vl_t;

__device__ __forceinline__ void gld16(const void* g, void* l) {
  // async global->LDS, 16B per lane; LDS dest = wave-uniform base + lane*16
  __builtin_amdgcn_global_load_lds((vg_t*)g, (vl_t*)l, 16, 0, 0);
}

// ---------------------------------------------------------------------------
// Fused fp32->fp16 convert of x, Wq, Wk, Wv in ONE dispatch.
// ---------------------------------------------------------------------------
__global__ __launch_bounds__(256) void cvt_all(const float* __restrict__ x,
                                               const float* __restrict__ wq,
                                               const float* __restrict__ wk,
                                               const float* __restrict__ wv,
                                               f16* __restrict__ xb,
                                               f16* __restrict__ wh) {
  const int bx = blockIdx.x;
  const float* in; f16* out; int base;
  if (bx < 8192)       { in = x;  out = xb;             base = bx; }
  else if (bx < 9216)  { in = wq; out = wh;             base = bx - 8192; }
  else if (bx < 10240) { in = wk; out = wh + (1 << 20); base = bx - 9216; }
  else                 { in = wv; out = wh + (2 << 20); base = bx - 10240; }
  const long i = ((long)base * 256 + threadIdx.x) * 4;
  float4 v = *(const float4*)(in + i);
  f16x4 o = { (f16)v.x, (f16)v.y, (f16)v.z, (f16)v.w };
  *(f16x4*)(out + i) = o;
}

// ---------------------------------------------------------------------------
// NT GEMM: C[m,n] = sum_k A[m,k]*B[n,k], fp16 in, fp32 accumulate.
// 128x128 tile, 4 waves (2x2 of 64x64), BK template (64/128).
// MFMA shape = 32x32x16 (was 16x16x32): same FLOPs and LDS bytes, but HALF
// the MFMA instruction count and a 20% higher pipe ceiling (m119: 4060 vs
// 3378 FLOP/cyc/CU). Three schedule variants (2-barrier, 8-phase, counted-
// vmcnt pipelines) all plateaued at ~31% MfmaUtil -> per-phase LDS-read time
// and MFMA issue time are serially additive; this cuts the MFMA term.
// Fragment layouts (gfx950):
//   A/B in: lane l holds row (l&31), k = (l>>5)*8 + [0..8)  (one f16x8)
//   C/D out: col = lane&31, row = (reg&3) + 8*(reg>>2) + 4*(lane>>5)
// MODE: 0 fp32 row-major, 1 fp16 row-major, 2 fp16 transposed C[n][m],
//       3 fused QKV epilogue (Q/K row-major f16, V transposed [p][B*S]).
// CAUSAL: 0 none, 1 skip tiles above diagonal (scores), 2 K-limit m0+128,
//         3 PV balanced 1D grid (512 blocks): anti-symmetric longest<->
//         shortest pairing -> per-CU Keff-sum constant.
// XOR chunk swizzle: LDS slot (row, j) holds global 16B chunk j ^ (row&(CH-1)).
// ---------------------------------------------------------------------------
template <int MODE, int CAUSAL, int BK>
__global__ __launch_bounds__(256) void gemm_bt(const f16* __restrict__ A, int lda, long aOffZ,
                                               const f16* __restrict__ B, int ldb, long bOffZ,
                                               void* __restrict__ Cv, int ldc, long cOffZ,
                                               int K) {
  constexpr int CH  = BK / 8;    // 16B chunks per row
  constexpr int RPL = 64 / CH;   // rows per wave-load
  constexpr int NL  = 32 / RPL;  // wave-loads per tile per wave
  __shared__ __align__(16) f16 lA[128 * BK];
  __shared__ __align__(16) f16 lB[128 * BK];

  const int tid  = threadIdx.x;
  const int wave = tid >> 6;
  const int lane = tid & 63;

  int m0, n0, z;
  if (CAUSAL == 3) {
    const int id   = blockIdx.x;
    const int item = (id < 256) ? id : 767 - id;
    const int mt   = 15 - (item >> 5);     // 32 blocks per Keff group
    const int j    = item & 31;
    m0 = mt * 128;
    n0 = (j & 7) * 128;
    z  = j >> 3;
  } else {
    m0 = blockIdx.x * 128;
    n0 = blockIdx.y * 128;
    z  = blockIdx.z;
  }

  if (CAUSAL == 1 && n0 >= m0 + 128) return;
  const int Keff = (CAUSAL >= 2) ? (m0 + 128) : K;

  const f16* Ab = A + (long)z * aOffZ + (long)m0 * lda;
  const f16* Bb = B + (long)z * bOffZ + (long)n0 * ldb;

  const int wm = (wave & 1) * 64;
  const int wn = (wave >> 1) * 64;

  f32x16 acc[2][2] = {};

  const int srow = lane / CH;    // staging row-within-group
  const int sj   = lane % CH;    // staging chunk
  const int fr32 = lane & 31;    // fragment row (A) / col (B)
  const int hi   = lane >> 5;    // k-chunk selector (0/1)

  for (int kt = 0; kt < Keff; kt += BK) {
    __syncthreads();  // previous iteration's ds_reads done
#pragma unroll
    for (int j = 0; j < NL; ++j) {
      const int rgrp = j * 4 + wave;
      const int row  = rgrp * RPL + srow;
      const int gch  = sj ^ (row & (CH - 1));
      gld16(Ab + (long)row * lda + kt + gch * 8, (void*)(lA + rgrp * 512 + lane * 8));
      gld16(Bb + (long)row * ldb + kt + gch * 8, (void*)(lB + rgrp * 512 + lane * 8));
    }
    __syncthreads();  // vmcnt drained -> staging visible

    // Per 16-k slice: 2 A-frags + 2 B-frags (ds_read_b128) + 4 MFMA.
#pragma unroll
    for (int ks = 0; ks < BK / 16; ++ks) {
      f16x8 af[2], bf[2];
#pragma unroll
      for (int i = 0; i < 2; ++i) {
        const int arow = wm + i * 32 + fr32;
        const int ach  = (ks * 2 + hi) ^ (arow & (CH - 1));
        af[i] = *(const f16x8*)(lA + arow * BK + ach * 8);
        const int brow = wn + i * 32 + fr32;
        const int bch  = (ks * 2 + hi) ^ (brow & (CH - 1));
        bf[i] = *(const f16x8*)(lB + brow * BK + bch * 8);
      }
#pragma unroll
      for (int mi = 0; mi < 2; ++mi)
#pragma unroll
        for (int ni = 0; ni < 2; ++ni)
          acc[mi][ni] = __builtin_amdgcn_mfma_f32_32x32x16_f16(af[mi], bf[ni], acc[mi][ni], 0, 0, 0);
    }
  }

  // Epilogue. C/D: col = lane&31, row = (reg&3) + 8*(reg>>2) + 4*(lane>>5).
#pragma unroll
  for (int mi = 0; mi < 2; ++mi) {
    const int rbase = m0 + wm + mi * 32 + 4 * hi;
#pragma unroll
    for (int ni = 0; ni < 2; ++ni) {
      const int col = n0 + wn + ni * 32 + fr32;
      if constexpr (MODE == 0) {
        float* C = (float*)Cv + (long)z * cOffZ;
#pragma unroll
        for (int g = 0; g < 4; ++g)
#pragma unroll
          for (int e = 0; e < 4; ++e)
            C[(long)(rbase + 8 * g + e) * ldc + col] = acc[mi][ni][4 * g + e];
      } else if constexpr (MODE == 1) {
        f16* C = (f16*)Cv + (long)z * cOffZ;
#pragma unroll
        for (int g = 0; g < 4; ++g)
#pragma unroll
          for (int e = 0; e < 4; ++e)
            C[(long)(rbase + 8 * g + e) * ldc + col] = (f16)acc[mi][ni][4 * g + e];
      } else if constexpr (MODE == 2) {
        f16* C = (f16*)Cv + (long)z * cOffZ;
#pragma unroll
        for (int g = 0; g < 4; ++g) {
          f16x4 o = { (f16)acc[mi][ni][4 * g + 0], (f16)acc[mi][ni][4 * g + 1],
                      (f16)acc[mi][ni][4 * g + 2], (f16)acc[mi][ni][4 * g + 3] };
          *(f16x4*)(C + (long)col * ldc + rbase + 8 * g) = o;  // rbase+8g % 4 == 0
        }
      } else {  // MODE 3: fused QKV routing (col band of 32 never straddles 1024-boundaries)
        f16* Qh  = (f16*)Cv;
        f16* Kh  = Qh + (size_t)8 * 1024 * 1024;
        f16* VTb = Kh + (size_t)8 * 1024 * 1024;
        if (col < 1024) {
#pragma unroll
          for (int g = 0; g < 4; ++g)
#pragma unroll
            for (int e = 0; e < 4; ++e)
              Qh[(long)(rbase + 8 * g + e) * DIM + col] = (f16)acc[mi][ni][4 * g + e];
        } else if (col < 2048) {
#pragma unroll
          for (int g = 0; g < 4; ++g)
#pragma unroll
            for (int e = 0; e < 4; ++e)
              Kh[(long)(rbase + 8 * g + e) * DIM + (col - 1024)] = (f16)acc[mi][ni][4 * g + e];
        } else {
#pragma unroll
          for (int g = 0; g < 4; ++g) {
            f16x4 o = { (f16)acc[mi][ni][4 * g + 0], (f16)acc[mi][ni][4 * g + 1],
                        (f16)acc[mi][ni][4 * g + 2], (f16)acc[mi][ni][4 * g + 3] };
            *(f16x4*)(VTb + (long)(col - 2048) * (BATCH * SEQ) + rbase + 8 * g) = o;
          }
        }
      }
    }
  }
}

// ---------------------------------------------------------------------------
// Causal softmax over f16 score rows, in-place (zero above diagonal).
// grid = (SEQ, BATCH), block = 256, 8 contiguous elems/thread (f16x8).
// Loads skipped above the diagonal; WRITES only the ceil((q+1)/128)*128 cols
// that PV's per-m-tile K-limit actually reads.
// ---------------------------------------------------------------------------
__global__ __launch_bounds__(256) void softmax_causal(f16* S) {
  const int q = blockIdx.x, b = blockIdx.y;
  f16* row = S + ((long)b * SEQ + q) * SEQ;
  const int tid = threadIdx.x;
  const int lane = tid & 63, wave = tid >> 6;
  const int nvalid = q + 1;
  const int kneed  = ((q >> 7) + 1) << 7;  // cols PV reads for this row

  f16x8 vv = {};
  if (tid * 8 < nvalid) vv = *(const f16x8*)(row + tid * 8);
  float v[8];
  float m = -3.0e38f;
#pragma unroll
  for (int i = 0; i < 8; ++i) {
    const int k = tid * 8 + i;
    v[i] = (k < nvalid) ? (float)vv[i] * 0.03125f : -3.0e38f;
    m = fmaxf(m, v[i]);
  }
#pragma unroll
  for (int off = 32; off; off >>= 1) m = fmaxf(m, __shfl_xor(m, off));
  __shared__ float redm[4], reds[4];
  if (lane == 0) redm[wave] = m;
  __syncthreads();
  m = fmaxf(fmaxf(redm[0], redm[1]), fmaxf(redm[2], redm[3]));

  float s = 0.f;
#pragma unroll
  for (int i = 0; i < 8; ++i) {
    const float p = (v[i] > -1.0e37f) ? __expf(v[i] - m) : 0.f;
    v[i] = p;
    s += p;
  }
#pragma unroll
  for (int off = 32; off; off >>= 1) s += __shfl_xor(s, off);
  if (lane == 0) reds[wave] = s;
  __syncthreads();
  s = reds[0] + reds[1] + reds[2] + reds[3];
  const float inv = 1.f / s;
  f16x8 o;
#pragma unroll
  for (int i = 0; i < 8; ++i) o[i] = (f16)(v[i] * inv);
  if (tid * 8 < kneed) *(f16x8*)(row + tid * 8) = o;
}

// ---------------------------------------------------------------------------
extern "C" void kernel_launch(void* const* d_in, const int* in_sizes, int n_in,
                              void* d_out, int out_size, void* d_ws, size_t ws_size,
                              hipStream_t stream) {
  const float* x  = (const float*)d_in[0];
  const float* Wq = (const float*)d_in[1];
  const float* Wk = (const float*)d_in[2];
  const float* Wv = (const float*)d_in[3];
  float* out = (float*)d_out;

  // ws layout (f16 elems): xb 8M | Wh 3M | Qh 8M | Kh 8M | VT 8M ([1024][8192]) |
  //                        Sc 16M f16 scores->probs in place (4 x 2048 x 2048)
  if (ws_size < (size_t)51 * 1024 * 1024 * 2) return;

  f16* xb = (f16*)d_ws;
  f16* Wh = xb + (size_t)8 * 1024 * 1024;
  f16* Qh = Wh + (size_t)3 * 1024 * 1024;
  f16* Kh = Qh + (size_t)8 * 1024 * 1024;
  f16* VT = Kh + (size_t)8 * 1024 * 1024;
  f16* Sc = VT + (size_t)8 * 1024 * 1024;

  const long QOFF = (long)SEQ * DIM;  // per-batch Q/K offset
  const long SOFF = (long)SEQ * SEQ;  // per-batch score offset (f16 elems)

  cvt_all<<<11264, 256, 0, stream>>>(x, Wq, Wk, Wv, xb, Wh);

  // Fused QKV: M=8192, N=3072 (Wq|Wk|Wv in Wh), K=1024. 128x128 tiles,
  // BK=64 -> 32 KiB LDS, ~5 blocks/CU; 32x32x16 MFMA.
  gemm_bt<3, 0, 64><<<dim3(64, 24, 1), 256, 0, stream>>>(xb, DIM, 0, Wh, DIM, 0, Qh, 0, 0, DIM);

  // scores = Q K^T (causal block-skip), f16 out, BK=128 (grid-limited occupancy)
  gemm_bt<1, 1, 128><<<dim3(16, 16, 4), 256, 0, stream>>>(Qh, DIM, QOFF, Kh, DIM, QOFF,
                                                          Sc, SEQ, SOFF, DIM);

  // causal softmax (scale 1/32), in-place f16 probs, zero above diagonal
  softmax_causal<<<dim3(SEQ, BATCH), 256, 0, stream>>>(Sc);

  // Z = P V  (A = probs f16 ld 2048; B = VT ld 8192; per-M-tile K-limit),
  // BK=128 + balanced 1D grid (longest<->shortest pairing kills the Keff tail)
  gemm_bt<0, 3, 128><<<dim3(512, 1, 1), 256, 0, stream>>>(Sc, SEQ, SOFF,
                                                          VT, BATCH * SEQ, SEQ,
                                                          out, DIM, (long)SEQ * DIM, SEQ);
}

// Round 6
// 238.133 us; speedup vs baseline: 1.0132x; 1.0132x over previous
//
#include <hip/hip_runtime.h>
#include <stdint.h>

#define SEQ   2048
#define DIM   1024
#define BATCH 4

typedef _Float16 f16;
typedef __attribute__((ext_vector_type(8))) _Float16 f16x8;
typedef __attribute__((ext_vector_type(4))) _Float16 f16x4;
typedef __attribute__((ext_vector_type(4))) float   f32x4;

typedef void __attribute__((address_space(1))) vg_t;
typedef void __attribute__((address_space(3))) vl_t;

__device__ __forceinline__ void gld16(const void* g, void* l) {
  // async global->LDS, 16B per lane; LDS dest = wave-uniform base + lane*16
  __builtin_amdgcn_global_load_lds((vg_t*)g, (vl_t*)l, 16, 0, 0);
}

// ---------------------------------------------------------------------------
// Fused fp32->fp16 convert of x, Wq, Wk, Wv in ONE dispatch.
// ---------------------------------------------------------------------------
__global__ __launch_bounds__(256) void cvt_all(const float* __restrict__ x,
                                               const float* __restrict__ wq,
                                               const float* __restrict__ wk,
                                               const float* __restrict__ wv,
                                               f16* __restrict__ xb,
                                               f16* __restrict__ wh) {
  const int bx = blockIdx.x;
  const float* in; f16* out; int base;
  if (bx < 8192)       { in = x;  out = xb;             base = bx; }
  else if (bx < 9216)  { in = wq; out = wh;             base = bx - 8192; }
  else if (bx < 10240) { in = wk; out = wh + (1 << 20); base = bx - 9216; }
  else                 { in = wv; out = wh + (2 << 20); base = bx - 10240; }
  const long i = ((long)base * 256 + threadIdx.x) * 4;
  float4 v = *(const float4*)(in + i);
  f16x4 o = { (f16)v.x, (f16)v.y, (f16)v.z, (f16)v.w };
  *(f16x4*)(out + i) = o;
}

// ---------------------------------------------------------------------------
// NT GEMM: C[m,n] = sum_k A[m,k]*B[n,k], fp16 in, fp32 accumulate.
// 128x128 tile, 4 waves (2x2 of 64x64), 16x16x32 MFMA, BK template.
// (r5 lesson: 32x32x16 halved MFMA instr count and VALUBusy 46->18 but
// duration and MfmaUtil were UNCHANGED and 6.3M LDS bank conflicts appeared
// -> neither issue pipe is binding; 16x16x32's fq-split read pattern is the
// conflict-free one. Reverted.)
// MODE: 0 fp32 row-major, 1 fp16 row-major, 2 fp16 transposed,
//       3 fused QKV epilogue (Q/K row-major f16, V transposed [p][B*S]).
// CAUSAL: 0 none, 1 skip tiles above diagonal, 2 K-limit m0+128 (PV),
//         3 PV balanced 1D grid (512 blocks): anti-symmetric longest<->
//         shortest pairing -> per-CU Keff-sum constant under round-robin.
// XOR chunk swizzle: LDS slot (row, j) holds global 16B chunk j ^ (row&(CH-1)).
// ---------------------------------------------------------------------------
template <int MODE, int CAUSAL, int BK>
__global__ __launch_bounds__(256) void gemm_bt(const f16* __restrict__ A, int lda, long aOffZ,
                                               const f16* __restrict__ B, int ldb, long bOffZ,
                                               void* __restrict__ Cv, int ldc, long cOffZ,
                                               int K) {
  constexpr int CH  = BK / 8;    // 16B chunks per row
  constexpr int RPL = 64 / CH;   // rows per wave-load
  constexpr int NL  = 32 / RPL;  // wave-loads per tile per wave
  __shared__ __align__(16) f16 lA[128 * BK];
  __shared__ __align__(16) f16 lB[128 * BK];

  const int tid  = threadIdx.x;
  const int wave = tid >> 6;
  const int lane = tid & 63;

  int m0, n0, z;
  if (CAUSAL == 3) {
    const int id   = blockIdx.x;
    const int item = (id < 256) ? id : 767 - id;
    const int mt   = 15 - (item >> 5);     // 32 blocks per Keff group
    const int j    = item & 31;
    m0 = mt * 128;
    n0 = (j & 7) * 128;
    z  = j >> 3;
  } else {
    m0 = blockIdx.x * 128;
    n0 = blockIdx.y * 128;
    z  = blockIdx.z;
  }

  if (CAUSAL == 1 && n0 >= m0 + 128) return;
  const int Keff = (CAUSAL >= 2) ? (m0 + 128) : K;

  const f16* Ab = A + (long)z * aOffZ + (long)m0 * lda;
  const f16* Bb = B + (long)z * bOffZ + (long)n0 * ldb;

  const int wm = (wave & 1) * 64;
  const int wn = (wave >> 1) * 64;

  f32x4 acc[4][4] = {};

  const int srow = lane / CH;
  const int sj   = lane % CH;
  const int fr   = lane & 15;
  const int fq   = lane >> 4;

  for (int kt = 0; kt < Keff; kt += BK) {
    __syncthreads();  // previous iteration's ds_reads done
#pragma unroll
    for (int j = 0; j < NL; ++j) {
      const int rgrp = j * 4 + wave;
      const int row  = rgrp * RPL + srow;
      const int gch  = sj ^ (row & (CH - 1));
      gld16(Ab + (long)row * lda + kt + gch * 8, (void*)(lA + rgrp * 512 + lane * 8));
      gld16(Bb + (long)row * ldb + kt + gch * 8, (void*)(lB + rgrp * 512 + lane * 8));
    }
    __syncthreads();  // vmcnt drained -> staging visible

#pragma unroll
    for (int kk = 0; kk < BK; kk += 32) {
      f16x8 af[4], bf[4];
#pragma unroll
      for (int i = 0; i < 4; ++i) {
        const int arow = wm + i * 16 + fr;
        const int ach  = (kk / 8 + fq) ^ (arow & (CH - 1));
        af[i] = *(const f16x8*)(lA + arow * BK + ach * 8);
        const int brow = wn + i * 16 + fr;
        const int bch  = (kk / 8 + fq) ^ (brow & (CH - 1));
        bf[i] = *(const f16x8*)(lB + brow * BK + bch * 8);
      }
#pragma unroll
      for (int mi = 0; mi < 4; ++mi)
#pragma unroll
        for (int ni = 0; ni < 4; ++ni)
          acc[mi][ni] = __builtin_amdgcn_mfma_f32_16x16x32_f16(af[mi], bf[ni], acc[mi][ni], 0, 0, 0);
    }
  }

  // Epilogue. C/D layout: col = lane&15, row = (lane>>4)*4 + reg
#pragma unroll
  for (int mi = 0; mi < 4; ++mi) {
    const int row = m0 + wm + mi * 16 + fq * 4;
#pragma unroll
    for (int ni = 0; ni < 4; ++ni) {
      const int col = n0 + wn + ni * 16 + fr;
      if constexpr (MODE == 0) {
        float* C = (float*)Cv + (long)z * cOffZ;
#pragma unroll
        for (int r = 0; r < 4; ++r) C[(long)(row + r) * ldc + col] = acc[mi][ni][r];
      } else if constexpr (MODE == 1) {
        f16* C = (f16*)Cv + (long)z * cOffZ;
#pragma unroll
        for (int r = 0; r < 4; ++r) C[(long)(row + r) * ldc + col] = (f16)acc[mi][ni][r];
      } else if constexpr (MODE == 2) {
        f16* C = (f16*)Cv + (long)z * cOffZ;
        f16x4 o = { (f16)acc[mi][ni][0], (f16)acc[mi][ni][1],
                    (f16)acc[mi][ni][2], (f16)acc[mi][ni][3] };
        *(f16x4*)(C + (long)col * ldc + row) = o;
      } else {  // MODE 3: fused QKV routing (wave-uniform regions)
        f16* Qh  = (f16*)Cv;
        f16* Kh  = Qh + (size_t)8 * 1024 * 1024;
        f16* VTb = Kh + (size_t)8 * 1024 * 1024;
        if (col < 1024) {
#pragma unroll
          for (int r = 0; r < 4; ++r) Qh[(long)(row + r) * DIM + col] = (f16)acc[mi][ni][r];
        } else if (col < 2048) {
#pragma unroll
          for (int r = 0; r < 4; ++r) Kh[(long)(row + r) * DIM + (col - 1024)] = (f16)acc[mi][ni][r];
        } else {
          f16x4 o = { (f16)acc[mi][ni][0], (f16)acc[mi][ni][1],
                      (f16)acc[mi][ni][2], (f16)acc[mi][ni][3] };
          *(f16x4*)(VTb + (long)(col - 2048) * (BATCH * SEQ) + row) = o;
        }
      }
    }
  }
}

// ---------------------------------------------------------------------------
// scores = Q K^T, causal, 128(M) x 96(N) tiles, BK=128, f16 out.
// WHY 96: causal tile count per batch becomes 187 -> grid 748 = 2.92 x 256,
// round-robin per-CU counts {2,3} of a 25.2 MF tile -> makespan 75.6 MF-units
// vs the 128-wide grid's 3 x 34.4 = 103 (544 = 2.125 x 256 quantized to 3).
// -27% scores makespan for +~56 MB extra Q re-fetch (LLC-absorbed).
// 4 waves tile 128x96 as 2x2 -> wave 64x48 (frags 4x3). LDS 56 KB.
// Compact 1D enumeration (no dead blocks). mt=15's last tile sticks out past
// col 2047: epilogue guards col<SEQ; OOB K-rows read harmless ws garbage that
// is never consumed (softmax masks k<nvalid; PV reads softmax-written cols).
// ---------------------------------------------------------------------------
__global__ __launch_bounds__(256) void scores_96(const f16* __restrict__ Qh,
                                                 const f16* __restrict__ Kh,
                                                 f16* __restrict__ Sc) {
  __shared__ __align__(16) f16 lA[128 * 128];
  __shared__ __align__(16) f16 lB[96 * 128];

  const int tid  = threadIdx.x;
  const int wave = tid >> 6;
  const int lane = tid & 63;
  const int srow = lane >> 4;   // CH=16 -> 4 rows per wave-load
  const int sj   = lane & 15;
  const int fr   = lane & 15;
  const int fq   = lane >> 4;
  const int wm   = (wave & 1) * 64;
  const int wn   = (wave >> 1) * 48;

  // decode compact causal tile index: per batch, m-tile mt has
  // floor((128*mt+127)/96)+1 n-tiles (n0 <= m0+127); total 187/batch.
  const int b = blockIdx.x;
  const int z = b / 187;
  int rem = b - z * 187;
  int mt = 0;
  while (true) {
    const int c = (128 * mt + 127) / 96 + 1;
    if (rem < c) break;
    rem -= c;
    ++mt;
  }
  const int m0 = mt * 128;
  const int n0 = rem * 96;

  const f16* Ab = Qh + (long)z * (SEQ * DIM) + (long)m0 * DIM;
  const f16* Bb = Kh + (long)z * (SEQ * DIM) + (long)n0 * DIM;

  f32x4 acc[4][3] = {};

  for (int kt = 0; kt < DIM; kt += 128) {
    __syncthreads();  // previous iteration's ds_reads done
#pragma unroll
    for (int j = 0; j < 8; ++j) {       // A: 128 rows = 32 wave-loads
      const int rgrp = j * 4 + wave;
      const int row  = rgrp * 4 + srow;
      const int gch  = sj ^ (row & 15);
      gld16(Ab + (long)row * DIM + kt + gch * 8, (void*)(lA + rgrp * 512 + lane * 8));
    }
#pragma unroll
    for (int j = 0; j < 6; ++j) {       // B: 96 rows = 24 wave-loads
      const int rgrp = j * 4 + wave;
      const int row  = rgrp * 4 + srow;
      const int gch  = sj ^ (row & 15);
      gld16(Bb + (long)row * DIM + kt + gch * 8, (void*)(lB + rgrp * 512 + lane * 8));
    }
    __syncthreads();  // vmcnt drained -> staging visible

#pragma unroll
    for (int kk = 0; kk < 128; kk += 32) {
      f16x8 af[4], bf[3];
#pragma unroll
      for (int i = 0; i < 4; ++i) {
        const int arow = wm + i * 16 + fr;
        const int ach  = (kk / 8 + fq) ^ (arow & 15);
        af[i] = *(const f16x8*)(lA + arow * 128 + ach * 8);
      }
#pragma unroll
      for (int i = 0; i < 3; ++i) {
        const int brow = wn + i * 16 + fr;
        const int bch  = (kk / 8 + fq) ^ (brow & 15);
        bf[i] = *(const f16x8*)(lB + brow * 128 + bch * 8);
      }
#pragma unroll
      for (int mi = 0; mi < 4; ++mi)
#pragma unroll
        for (int ni = 0; ni < 3; ++ni)
          acc[mi][ni] = __builtin_amdgcn_mfma_f32_16x16x32_f16(af[mi], bf[ni], acc[mi][ni], 0, 0, 0);
    }
  }

  f16* C = Sc + (long)z * SEQ * SEQ;
#pragma unroll
  for (int mi = 0; mi < 4; ++mi) {
    const int row = m0 + wm + mi * 16 + fq * 4;
#pragma unroll
    for (int ni = 0; ni < 3; ++ni) {
      const int col = n0 + wn + ni * 16 + fr;
      if (col < SEQ) {
#pragma unroll
        for (int r = 0; r < 4; ++r)
          C[(long)(row + r) * SEQ + col] = (f16)acc[mi][ni][r];
      }
    }
  }
}

// ---------------------------------------------------------------------------
// Causal softmax over f16 score rows, in-place (zero above diagonal).
// grid = (SEQ, BATCH), block = 256, 8 contiguous elems/thread (f16x8).
// Loads skipped above the diagonal; WRITES only the ceil((q+1)/128)*128 cols
// that PV's per-m-tile K-limit actually reads.
// ---------------------------------------------------------------------------
__global__ __launch_bounds__(256) void softmax_causal(f16* S) {
  const int q = blockIdx.x, b = blockIdx.y;
  f16* row = S + ((long)b * SEQ + q) * SEQ;
  const int tid = threadIdx.x;
  const int lane = tid & 63, wave = tid >> 6;
  const int nvalid = q + 1;
  const int kneed  = ((q >> 7) + 1) << 7;  // cols PV reads for this row

  f16x8 vv = {};
  if (tid * 8 < nvalid) vv = *(const f16x8*)(row + tid * 8);
  float v[8];
  float m = -3.0e38f;
#pragma unroll
  for (int i = 0; i < 8; ++i) {
    const int k = tid * 8 + i;
    v[i] = (k < nvalid) ? (float)vv[i] * 0.03125f : -3.0e38f;
    m = fmaxf(m, v[i]);
  }
#pragma unroll
  for (int off = 32; off; off >>= 1) m = fmaxf(m, __shfl_xor(m, off));
  __shared__ float redm[4], reds[4];
  if (lane == 0) redm[wave] = m;
  __syncthreads();
  m = fmaxf(fmaxf(redm[0], redm[1]), fmaxf(redm[2], redm[3]));

  float s = 0.f;
#pragma unroll
  for (int i = 0; i < 8; ++i) {
    const float p = (v[i] > -1.0e37f) ? __expf(v[i] - m) : 0.f;
    v[i] = p;
    s += p;
  }
#pragma unroll
  for (int off = 32; off; off >>= 1) s += __shfl_xor(s, off);
  if (lane == 0) reds[wave] = s;
  __syncthreads();
  s = reds[0] + reds[1] + reds[2] + reds[3];
  const float inv = 1.f / s;
  f16x8 o;
#pragma unroll
  for (int i = 0; i < 8; ++i) o[i] = (f16)(v[i] * inv);
  if (tid * 8 < kneed) *(f16x8*)(row + tid * 8) = o;
}

// ---------------------------------------------------------------------------
extern "C" void kernel_launch(void* const* d_in, const int* in_sizes, int n_in,
                              void* d_out, int out_size, void* d_ws, size_t ws_size,
                              hipStream_t stream) {
  const float* x  = (const float*)d_in[0];
  const float* Wq = (const float*)d_in[1];
  const float* Wk = (const float*)d_in[2];
  const float* Wv = (const float*)d_in[3];
  float* out = (float*)d_out;

  // ws layout (f16 elems): xb 8M | Wh 3M | Qh 8M | Kh 8M | VT 8M ([1024][8192]) |
  //                        Sc 16M f16 scores->probs in place (4 x 2048 x 2048)
  if (ws_size < (size_t)51 * 1024 * 1024 * 2) return;

  f16* xb = (f16*)d_ws;
  f16* Wh = xb + (size_t)8 * 1024 * 1024;
  f16* Qh = Wh + (size_t)3 * 1024 * 1024;
  f16* Kh = Qh + (size_t)8 * 1024 * 1024;
  f16* VT = Kh + (size_t)8 * 1024 * 1024;
  f16* Sc = VT + (size_t)8 * 1024 * 1024;

  const long SOFF = (long)SEQ * SEQ;  // per-batch score offset (f16 elems)

  cvt_all<<<11264, 256, 0, stream>>>(x, Wq, Wk, Wv, xb, Wh);

  // Fused QKV: M=8192, N=3072 (Wq|Wk|Wv in Wh), K=1024. 128x128 tiles,
  // BK=64 -> 32 KiB LDS, ~5 blocks/CU; 16x16x32 MFMA (r0-proven 68.2us).
  gemm_bt<3, 0, 64><<<dim3(64, 24, 1), 256, 0, stream>>>(xb, DIM, 0, Wh, DIM, 0, Qh, 0, 0, DIM);

  // scores = Q K^T (causal), 128x96 tiles, compact 748-block grid (2.92/CU)
  scores_96<<<748, 256, 0, stream>>>(Qh, Kh, Sc);

  // causal softmax (scale 1/32), in-place f16 probs, zero above diagonal
  softmax_causal<<<dim3(SEQ, BATCH), 256, 0, stream>>>(Sc);

  // Z = P V  (A = probs f16 ld 2048; B = VT ld 8192; per-M-tile K-limit),
  // BK=128 + balanced 1D grid (longest<->shortest pairing kills the Keff tail)
  gemm_bt<0, 3, 128><<<dim3(512, 1, 1), 256, 0, stream>>>(Sc, SEQ, SOFF,
                                                          VT, BATCH * SEQ, SEQ,
                                                          out, DIM, (long)SEQ * DIM, SEQ);
}